// Round 5
// baseline (126.234 us; speedup 1.0000x reference)
//
#include <hip/hip_runtime.h>
#include <hip/hip_bf16.h>

#define B_ 128
#define L_ 196
#define D_ 1024

typedef __attribute__((ext_vector_type(8))) short short8v;
typedef __attribute__((ext_vector_type(4))) float f32x4;
typedef unsigned short ushort_t;

// d_ws layout (bytes). Max footprint 60,293,120.
#define OFF_ATTBF   0UL          // 25088*1024*2 = 51,380,224
#define OFF_WBF     51380224UL   // 1024*1024*2  =  2,097,152
#define OFF_A2      53477376UL   // 128*2048*2   =    524,288   [x|h] bf16
#define OFF_W2      54001664UL   // 1024*2048*2  =  4,194,304   [Wi|Wh] bf16
#define OFF_SPART   53477376UL   // 16*25088*4   =  1,605,632   (aliases A2/W2: dead before score)
#define OFF_CPART   58195968UL   // 4*128*1024*4 =  2,097,152   c partials

__device__ inline unsigned short f2bf(float f) {
  unsigned int u = __float_as_uint(f);
  unsigned int r = (u + 0x7fffu + ((u >> 16) & 1u)) >> 16;
  return (unsigned short)r;
}

// ---------------- convert: fp32 -> bf16 staging buffers ----------------
__global__ void convert_kernel(const float* __restrict__ att, const float* __restrict__ Wa,
                               const float* __restrict__ x,   const float* __restrict__ h,
                               const float* __restrict__ Wi,  const float* __restrict__ Wh,
                               ushort_t* __restrict__ att_bf, ushort_t* __restrict__ W_bf,
                               ushort_t* __restrict__ A2,     ushort_t* __restrict__ W2) {
  const int n0 = (B_*L_*D_)/4;
  const int n1 = (D_*D_)/4;
  const int n2 = (B_*D_)/4;
  const int total = n0 + n1 + 2*n2 + 2*n1;
  for (int idx = blockIdx.x*blockDim.x + threadIdx.x; idx < total;
       idx += gridDim.x*blockDim.x) {
    const float4* src; ushort_t* dst;
    int i = idx;
    if (i < n0)               { src = (const float4*)att + i; dst = att_bf + (size_t)i*4; }
    else if ((i -= n0) < n1)  { src = (const float4*)Wa  + i; dst = W_bf  + (size_t)i*4; }
    else if ((i -= n1) < n2)  { int b = i>>8, k4 = i&255; src = (const float4*)x  + i; dst = A2 + b*2048 + k4*4; }
    else if ((i -= n2) < n2)  { int b = i>>8, k4 = i&255; src = (const float4*)h  + i; dst = A2 + b*2048 + 1024 + k4*4; }
    else if ((i -= n2) < n1)  { int e = i>>8, k4 = i&255; src = (const float4*)Wi + i; dst = W2 + e*2048 + k4*4; }
    else { i -= n1;             int e = i>>8, k4 = i&255; src = (const float4*)Wh + i; dst = W2 + e*2048 + 1024 + k4*4; }
    float4 v = *src;
    ushort4 o; o.x = f2bf(v.x); o.y = f2bf(v.y); o.z = f2bf(v.z); o.w = f2bf(v.w);
    *(ushort4*)dst = o;
  }
}

// ---------------- c-matrix GEMM, split-K x4 (grid 32) ----------------
__device__ inline void stage_tile(const ushort_t* __restrict__ g, int row0, int Kld, int k0,
                                  ushort_t* ldst, int t) {
  #pragma unroll
  for (int it = 0; it < 4; ++it) {
    int linear = it*4096 + t*16;
    int r = linear >> 7;
    int c = (t & 7) ^ (r & 7);
    const ushort_t* src = g + (size_t)(row0 + r)*Kld + k0 + c*8;
    ushort_t* dst = ldst + ((it*4096 + ((t & 192) << 4)) >> 1);
    __builtin_amdgcn_global_load_lds((const __attribute__((address_space(1))) void*)src,
                                     (__attribute__((address_space(3))) void*)dst,
                                     16, 0, 0);
  }
}

__device__ inline short8v ldfrag(const ushort_t* tile, int row, int c) {
  int phys = c ^ (row & 7);
  return *(const short8v*)(tile + row*64 + phys*8);
}

__global__ __launch_bounds__(256) void gemm_c_kernel(
    const ushort_t* __restrict__ Amat, const ushort_t* __restrict__ Bmat,
    float* __restrict__ cpart) {
  __shared__ ushort_t lds[32768];
  int bid = blockIdx.x;
  int e0 = (bid & 7)*128;
  int kc = bid >> 3;               // 0..3, K-chunk of 512
  int kbeg = kc*512;
  const int Kld = 2048;
  int t = threadIdx.x, lane = t & 63, w = t >> 6;
  int wm = w >> 1, we = w & 1;
  int lrow = lane & 15;
  int lk = lane >> 4;

  f32x4 acc[4][4];
  #pragma unroll
  for (int i = 0; i < 4; ++i)
    #pragma unroll
    for (int j = 0; j < 4; ++j) acc[i][j] = (f32x4){0.f, 0.f, 0.f, 0.f};

  stage_tile(Amat, 0,  Kld, kbeg, lds, t);
  stage_tile(Bmat, e0, Kld, kbeg, lds + 8192, t);
  __syncthreads();

  const int nk = 8;                // 512 / 64
  for (int kt = 0; kt < nk; ++kt) {
    int cur = kt & 1;
    if (kt + 1 < nk) {
      stage_tile(Amat, 0,  Kld, kbeg + ((kt+1) << 6), lds + (cur^1)*16384, t);
      stage_tile(Bmat, e0, Kld, kbeg + ((kt+1) << 6), lds + (cur^1)*16384 + 8192, t);
    }
    const ushort_t* At = lds + cur*16384;
    const ushort_t* Bt = At + 8192;
    #pragma unroll
    for (int hh = 0; hh < 2; ++hh) {
      short8v af[4], bfv[4];
      #pragma unroll
      for (int i = 0; i < 4; ++i) af[i]  = ldfrag(At, wm*64 + i*16 + lrow, hh*4 + lk);
      #pragma unroll
      for (int j = 0; j < 4; ++j) bfv[j] = ldfrag(Bt, we*64 + j*16 + lrow, hh*4 + lk);
      #pragma unroll
      for (int i = 0; i < 4; ++i)
        #pragma unroll
        for (int j = 0; j < 4; ++j)
          acc[i][j] = __builtin_amdgcn_mfma_f32_16x16x32_bf16(af[i], bfv[j], acc[i][j], 0, 0, 0);
    }
    __syncthreads();
  }

  float* outc = cpart + (size_t)kc*131072;   // [128][1024] raw partial (no bias)
  #pragma unroll
  for (int i = 0; i < 4; ++i) {
    int m = wm*64 + i*16 + lk*4;
    #pragma unroll
    for (int j = 0; j < 4; ++j) {
      int e = e0 + we*64 + j*16 + lrow;
      #pragma unroll
      for (int r = 0; r < 4; ++r)
        outc[(m + r)*1024 + e] = acc[i][j][r];
    }
  }
}

// ---------------- 256x256 score GEMM: fat-region K-tiles, 2 barriers/K-tile ----------------
__device__ inline short8v ldfrag2(const ushort_t* tile, int row, int c) {
  int phys = c ^ (row & 7);
  return *(const short8v*)(tile + row*64 + phys*8);   // ds_read_b128, 2-way max
}

#define STAGE(lanebase, half, kt, ldsT) { \
    const ushort_t* s0_ = (lanebase) + (half)*131072 + (kt)*64; \
    ushort_t* d0_ = (ldsT) + (half)*8192 + w*512; \
    __builtin_amdgcn_global_load_lds((const __attribute__((address_space(1))) void*)s0_, \
                                     (__attribute__((address_space(3))) void*)d0_, 16, 0, 0); \
    __builtin_amdgcn_global_load_lds((const __attribute__((address_space(1))) void*)(s0_ + 65536), \
                                     (__attribute__((address_space(3))) void*)(d0_ + 4096), 16, 0, 0); }

#define BARR()  __builtin_amdgcn_s_barrier()
#define VM8()   asm volatile("s_waitcnt vmcnt(8)" ::: "memory")

// k-major read macros into DISJOINT named frag arrays (WAR-free rolling window)
#define RD_ALO_K(base, kk) { _Pragma("unroll") for (int i_=0;i_<4;++i_) \
    aLo[i_][kk] = ldfrag2(base, wm*64 + i_*16 + lrow, (kk)*4 + lk); }
#define RD_AHI_K(base, kk) { _Pragma("unroll") for (int i_=0;i_<4;++i_) \
    aHi[i_][kk] = ldfrag2(base, 128 + wm*64 + i_*16 + lrow, (kk)*4 + lk); }
#define RD_B01_K(base, kk) { _Pragma("unroll") for (int j_=0;j_<2;++j_) \
    b01[j_][kk] = ldfrag2(base, wn*64 + j_*16 + lrow, (kk)*4 + lk); }
#define RD_B23_K(base, kk) { _Pragma("unroll") for (int j_=0;j_<2;++j_) \
    b23[j_][kk] = ldfrag2(base, wn*64 + (2+j_)*16 + lrow, (kk)*4 + lk); }

// one C-quadrant over K=64: k-major (8 independent MFMAs between dependent pairs)
#define MQ(I0, J0, A_, B_) { _Pragma("unroll") for (int k_=0;k_<2;++k_) { \
    _Pragma("unroll") for (int i_=0;i_<4;++i_) { _Pragma("unroll") for (int j_=0;j_<2;++j_) { \
      acc[(I0)+i_][(J0)+j_] = __builtin_amdgcn_mfma_f32_16x16x32_bf16(A_[i_][k_], B_[j_][k_], acc[(I0)+i_][(J0)+j_], 0,0,0); } } } }

// whole-K-tile compute region: reads lead their consuming quadrants; the compiler
// schedules fine-grained lgkmcnt so the read burst overlaps MFMA issue.
#define KTILE_BODY(Abuf, Bbuf) \
    RD_ALO_K(Abuf, 0); RD_B01_K(Bbuf, 0); RD_B23_K(Bbuf, 0); \
    RD_ALO_K(Abuf, 1); RD_B01_K(Bbuf, 1); RD_B23_K(Bbuf, 1); \
    MQ(0, 0, aLo, b01); \
    RD_AHI_K(Abuf, 0); RD_AHI_K(Abuf, 1); \
    MQ(0, 2, aLo, b23); \
    MQ(4, 0, aHi, b01); \
    MQ(4, 2, aHi, b23);

__global__ __launch_bounds__(512, 2) void gemm_score_kernel(
    const ushort_t* __restrict__ Amat, const ushort_t* __restrict__ Bmat,
    const float* __restrict__ cpart,
    const float* __restrict__ ba, const float* __restrict__ bh, const float* __restrict__ bi,
    const float* __restrict__ wd,
    float* __restrict__ spart) {
  __shared__ ushort_t lds[65536];   // 128 KB: A0 B0 A1 B1, 32KB each
  __shared__ float c_lds[768];      // [3][256]: c+biases for this block's (bb,e) range
  const int nk = 16;
  int bid = blockIdx.x;
  int swz = (bid & 7)*49 + (bid >> 3);     // 392 % 8 == 0 -> bijective XCD swizzle
  int m_blk = swz >> 2, e_blk = swz & 3;
  int m0 = m_blk*256, e0 = e_blk*256;
  int t = (int)threadIdx.x, lane = t & 63, w = t >> 6;
  int wm = w >> 2, wn = w & 3;
  int lrow = lane & 15, lk = lane >> 4;

  // c_lds = biases + sum of 4 K-partials (consumed in epilogue; loop barriers order it)
  int bb0 = m0 / 196;
  for (int idx = t; idx < 768; idx += 512) {
    int bb = bb0 + (idx >> 8);
    int e  = e0 + (idx & 255);
    float v = ba[e] + bh[e] + bi[e];
    if (bb < 128) {
      v += cpart[bb*1024 + e] + cpart[131072 + bb*1024 + e]
         + cpart[262144 + bb*1024 + e] + cpart[393216 + bb*1024 + e];
    }
    c_lds[idx] = v;
  }

  // per-lane staging base pointers (row r0 = t>>3, chunk c0 = (t&7)^(r0&7))
  int r0 = t >> 3;
  int c0 = (t & 7) ^ (r0 & 7);
  const ushort_t* aBase = Amat + (size_t)(m0 + r0)*1024 + c0*8;
  const ushort_t* bBase = Bmat + (size_t)(e0 + r0)*1024 + c0*8;

  ushort_t* A0_ = lds;
  ushort_t* B0_ = lds + 16384;
  ushort_t* A1_ = lds + 32768;
  ushort_t* B1_ = lds + 49152;

  f32x4 acc[8][4];
  #pragma unroll
  for (int i = 0; i < 8; ++i)
    #pragma unroll
    for (int j = 0; j < 4; ++j) acc[i][j] = (f32x4){0.f, 0.f, 0.f, 0.f};
  short8v aLo[4][2], aHi[4][2], b01[2][2], b23[2][2];

  // prologue: stage K-tiles 0 (buf0) and 1 (buf1) = 16 loads/thread outstanding
  STAGE(aBase, 0, 0, A0_); STAGE(aBase, 1, 0, A0_);
  STAGE(bBase, 0, 0, B0_); STAGE(bBase, 1, 0, B0_);
  STAGE(aBase, 0, 1, A1_); STAGE(aBase, 1, 1, A1_);
  STAGE(bBase, 0, 1, B1_); STAGE(bBase, 1, 1, B1_);

  for (int it2 = 0; it2 < 8; ++it2) {
    int kt = 2*it2;
    // ---- K-tile kt (buf0) ----
    VM8();       // oldest 8 drained -> tile kt landed (tile kt+1's 8 stay in flight)
    BARR();      // all waves' portions landed + buf0 free (last read 2 tiles ago)
    KTILE_BODY(A0_, B0_);
    BARR();      // all waves' buf0 reads serviced (gated by their MFMA lgkm waits)
    { int ks = (kt+2 < nk) ? kt+2 : nk-1;    // tail: re-stage tile 15 (never read)
      STAGE(aBase, 0, ks, A0_); STAGE(aBase, 1, ks, A0_);
      STAGE(bBase, 0, ks, B0_); STAGE(bBase, 1, ks, B0_); }
    // ---- K-tile kt+1 (buf1) ----
    VM8();
    BARR();
    KTILE_BODY(A1_, B1_);
    BARR();
    { int ks = (kt+3 < nk) ? kt+3 : nk-1;
      STAGE(aBase, 0, ks, A1_); STAGE(aBase, 1, ks, A1_);
      STAGE(bBase, 0, ks, B1_); STAGE(bBase, 1, ks, B1_); }
  }

  // epilogue: partial score = sum_e tanh(acc + c) * wd[e]; spart[p][m], float4 stores
  int p = e_blk*4 + wn;
  #pragma unroll
  for (int i = 0; i < 8; ++i) {
    int mbase = m0 + (i>>2)*128 + wm*64 + (i&3)*16 + lk*4;
    f32x4 ps;
    #pragma unroll
    for (int r = 0; r < 4; ++r) {
      int m = mbase + r;
      int bb = (int)((unsigned)m / 196u);
      float partial = 0.f;
      #pragma unroll
      for (int j = 0; j < 4; ++j) {
        int ee = wn*64 + j*16 + lrow;
        float v = acc[i][j][r] + c_lds[(bb - bb0)*256 + ee];
        float ex = __expf(2.f*v);
        partial += (1.f - 2.f/(ex + 1.f)) * wd[e0 + ee];
      }
      partial += __shfl_xor(partial, 1);
      partial += __shfl_xor(partial, 2);
      partial += __shfl_xor(partial, 4);
      partial += __shfl_xor(partial, 8);
      ps[r] = partial;
    }
    if (lrow == 0) *(f32x4*)(spart + (size_t)p*25088 + mbase) = ps;
  }
}

// ---------------- finalize: softmax over L, weighted sum of bf16 att ----------------
__global__ __launch_bounds__(256) void finalize_kernel(const ushort_t* __restrict__ att_bf,
                                                       const float* __restrict__ spart,
                                                       float* __restrict__ out) {
  int b  = blockIdx.x >> 1;
  int dh = blockIdx.x & 1;
  int t  = threadIdx.x;
  __shared__ float wls[L_];
  __shared__ float red[8];

  float s = -1e30f;
  if (t < L_) {
    int m = b*L_ + t;
    float sum = 0.f;
    #pragma unroll
    for (int p = 0; p < 16; ++p) sum += spart[p*25088 + m];
    s = sum;                       // b_d2d omitted: softmax shift-invariant
  }
  float mx = s;
  #pragma unroll
  for (int off = 1; off < 64; off <<= 1) mx = fmaxf(mx, __shfl_xor(mx, off));
  if ((t & 63) == 0) red[t >> 6] = mx;
  __syncthreads();
  mx = fmaxf(fmaxf(red[0], red[1]), fmaxf(red[2], red[3]));
  float pr = (t < L_) ? __expf(s - mx) : 0.f;
  float ssum = pr;
  #pragma unroll
  for (int off = 1; off < 64; off <<= 1) ssum += __shfl_xor(ssum, off);
  if ((t & 63) == 0) red[4 + (t >> 6)] = ssum;
  __syncthreads();
  float tot = red[4] + red[5] + red[6] + red[7];
  if (t < L_) wls[t] = pr / tot;
  __syncthreads();

  int d = dh*512 + t*2;
  const ushort_t* abase = att_bf + (size_t)b*L_*D_ + d;
  float a0 = 0.f, a1 = 0.f;
  #pragma unroll 4
  for (int l = 0; l < L_; ++l) {
    float wv = wls[l];
    unsigned int v = *(const unsigned int*)(abase + (size_t)l*D_);
    float lo = __uint_as_float(v << 16);
    float hi = __uint_as_float(v & 0xffff0000u);
    a0 += wv*lo; a1 += wv*hi;
  }
  float2 o; o.x = a0; o.y = a1;
  *(float2*)(out + (size_t)b*D_ + d) = o;
}

extern "C" void kernel_launch(void* const* d_in, const int* in_sizes, int n_in,
                              void* d_out, int out_size, void* d_ws, size_t ws_size,
                              hipStream_t stream) {
  (void)in_sizes; (void)n_in; (void)out_size; (void)ws_size;
  const float* x   = (const float*)d_in[0];
  const float* att = (const float*)d_in[1];
  const float* h   = (const float*)d_in[2];
  const float* Wa  = (const float*)d_in[3];
  const float* ba  = (const float*)d_in[4];
  const float* Wh  = (const float*)d_in[5];
  const float* bh  = (const float*)d_in[6];
  const float* Wi  = (const float*)d_in[7];
  const float* bi  = (const float*)d_in[8];
  const float* wd  = (const float*)d_in[9];
  // d_in[10] = b_d2d: softmax shift-invariant, unused

  char* ws = (char*)d_ws;
  ushort_t* att_bf = (ushort_t*)(ws + OFF_ATTBF);
  ushort_t* W_bf   = (ushort_t*)(ws + OFF_WBF);
  ushort_t* A2     = (ushort_t*)(ws + OFF_A2);
  ushort_t* W2     = (ushort_t*)(ws + OFF_W2);
  float*    cpart  = (float*)(ws + OFF_CPART);
  float*    spart  = (float*)(ws + OFF_SPART);
  float*    out    = (float*)d_out;

  hipLaunchKernelGGL(convert_kernel, dim3(2048), dim3(256), 0, stream,
                     att, Wa, x, h, Wi, Wh, att_bf, W_bf, A2, W2);
  hipLaunchKernelGGL(gemm_c_kernel, dim3(32), dim3(256), 0, stream,
                     A2, W2, cpart);
  hipLaunchKernelGGL(gemm_score_kernel, dim3(392), dim3(512), 0, stream,
                     att_bf, W_bf, cpart, ba, bh, bi, wd, spart);
  hipLaunchKernelGGL(finalize_kernel, dim3(256), dim3(256), 0, stream,
                     att_bf, spart, out);
}